// Round 1
// baseline (94.518 us; speedup 1.0000x reference)
//
#include <hip/hip_runtime.h>
#include <math.h>

#define NB 8
#define NT 512
#define NM 8
#define ND 128
#define NQ 16
#define NW 16

// ---------------- init: Ramanujan FIR bank (matches numpy double math) ----------------
__global__ void rama_init_k(float* __restrict__ Kf) {
    int qi = (int)threadIdx.x;          // 0..15 -> q = qi+1
    if (qi >= 16) return;
    int q1 = qi + 1;
    double c[16];
    for (int n = 0; n < 16; ++n) c[n] = 0.0;
    for (int a = 1; a <= q1; ++a) {
        int x = a, y = q1;
        while (y) { int r = x % y; x = y; y = r; }
        if (x == 1) {
            double scale = 2.0 * 3.14159265358979323846 / (double)q1;
            for (int n = 0; n < 16; ++n)
                c[n] += cos((double)(a * n) * scale);
        }
    }
    double mean = 0.0;
    for (int n = 0; n < 16; ++n) mean += c[n];
    mean *= (1.0 / 16.0);
    double ss = 0.0;
    for (int n = 0; n < 16; ++n) { c[n] -= mean; ss += c[n] * c[n]; }
    double denom = sqrt(ss > 1e-6 ? ss : 1e-6);
    for (int n = 0; n < 16; ++n) Kf[qi * 16 + n] = (float)(c[n] / denom);
}

// ---------------- kernel 1: z_anl[b,m,t] = mean_d z[b,t,m,d] * vm[b,t,m] ----------------
__global__ __launch_bounds__(256) void rama_reduce_k(
    const float* __restrict__ z, const float* __restrict__ vm,
    float* __restrict__ za)
{
    const int row  = blockIdx.x * 4 + (threadIdx.x >> 6);   // (b*T+t)*M + m
    const int lane = threadIdx.x & 63;
    const float2 v = *(const float2*)(z + (size_t)row * ND + lane * 2);
    float s = v.x + v.y;
    #pragma unroll
    for (int off = 32; off; off >>= 1) s += __shfl_xor(s, off, 64);
    if (lane == 0) {
        const int m = row & 7;
        const int t = (row >> 3) & 511;
        const int b = row >> 12;
        za[(b * NM + m) * NT + t] = (s * (1.0f / 128.0f)) * vm[row];
    }
}

// ---------------- kernel 2: fused gate + synthesis ----------------
__global__ __launch_bounds__(256) void rama_fuse_k(
    const float* __restrict__ z, const float* __restrict__ vm,
    const float* __restrict__ gw1, const float* __restrict__ gb1,
    const float* __restrict__ gw2, const float* __restrict__ gb2,
    const float* __restrict__ beta,
    const float* __restrict__ Kf, const float* __restrict__ za,
    float* __restrict__ out)
{
    __shared__ __align__(16) float Ks[256];
    __shared__ __align__(16) float effs[64][16];
    __shared__ float vms[64];

    const int tid   = threadIdx.x;
    const int blk   = blockIdx.x;
    const int chunk = blk & 7;          // T/64 = 8
    const int m     = (blk >> 3) & 7;
    const int b     = blk >> 6;
    const int t0    = chunk * 64;

    Ks[tid] = Kf[tid];
    __syncthreads();

    // ---- issue global loads for phase B early (overlap with gate compute) ----
    const int wv   = tid >> 6;
    const int lane = tid & 63;
    const int tsub = t0 + wv * 16;
    float2 zr[31];
    #pragma unroll
    for (int j = 0; j < 31; ++j) {
        const int t = tsub - 15 + j;
        if (t >= 0) {
            zr[j] = *(const float2*)(z + (((size_t)b * NT + t) * NM + m) * ND + lane * 2);
        } else { zr[j].x = 0.0f; zr[j].y = 0.0f; }
    }

    // ---- phase A: gates for 64 timesteps (wave 0) ----
    if (tid < 64) {
        const int t = t0 + tid;
        const float* zab = za + b * (NM * NT);
        float rg[16];
        #pragma unroll
        for (int m2 = 0; m2 < 8; ++m2) {
            float zwl[16];
            #pragma unroll
            for (int dly = 0; dly < 16; ++dly) {
                const int tt = t - dly;
                zwl[dly] = (tt >= 0) ? zab[m2 * NT + tt] : 0.0f;
            }
            #pragma unroll
            for (int h = 0; h < 2; ++h) {
                const float* kr = &Ks[(2 * m + h) * 16];
                float acc = 0.0f;
                #pragma unroll
                for (int dly = 0; dly < 16; ++dly)
                    acc = fmaf(kr[15 - dly], zwl[dly], acc);
                rg[h * 8 + m2] = acc;   // q' = h*8 + m2 (scramble mapping)
            }
        }
        float h1[16];
        #pragma unroll
        for (int q = 0; q < 16; ++q) {
            const float v = fmaf(rg[q], gw1[q], gb1[q]);
            h1[q] = 0.5f * v * (1.0f + erff(v * 0.70710678118654752440f));
        }
        float g[16];
        #pragma unroll
        for (int p = 0; p < 16; ++p) {
            float acc = gb2[p];
            #pragma unroll
            for (int q = 0; q < 16; ++q) acc = fmaf(h1[q], gw2[p * 16 + q], acc);
            g[p] = 1.0f / (1.0f + expf(-acc));
        }
        float eff16[16];
        #pragma unroll
        for (int dly = 0; dly < 16; ++dly) {
            float acc = 0.0f;
            #pragma unroll
            for (int p = 0; p < 16; ++p) acc = fmaf(Ks[p * 16 + 15 - dly], g[p], acc);
            const int tt = t - dly;
            const float v = (tt >= 0) ? vm[((size_t)b * NT + tt) * NM + m] : 0.0f;
            eff16[dly] = acc * v;       // fold mask into taps
        }
        float4* er = (float4*)&effs[tid][0];
        er[0] = make_float4(eff16[0],  eff16[1],  eff16[2],  eff16[3]);
        er[1] = make_float4(eff16[4],  eff16[5],  eff16[6],  eff16[7]);
        er[2] = make_float4(eff16[8],  eff16[9],  eff16[10], eff16[11]);
        er[3] = make_float4(eff16[12], eff16[13], eff16[14], eff16[15]);
        vms[tid] = vm[((size_t)b * NT + t) * NM + m];
    }
    __syncthreads();

    // ---- phase B: 16-tap synthesis, each wave does 16 timesteps x 128 d ----
    const float bet = beta[0];
    #pragma unroll
    for (int i = 0; i < 16; ++i) {
        const float* erow = &effs[wv * 16 + i][0];
        const float4 e0 = *(const float4*)(erow + 0);
        const float4 e1 = *(const float4*)(erow + 4);
        const float4 e2 = *(const float4*)(erow + 8);
        const float4 e3 = *(const float4*)(erow + 12);
        float px = 0.0f, py = 0.0f;
        #define ACC(EV, DLY) { const float2 zv = zr[15 + i - (DLY)]; \
                               px = fmaf((EV), zv.x, px); py = fmaf((EV), zv.y, py); }
        ACC(e0.x, 0)  ACC(e0.y, 1)  ACC(e0.z, 2)  ACC(e0.w, 3)
        ACC(e1.x, 4)  ACC(e1.y, 5)  ACC(e1.z, 6)  ACC(e1.w, 7)
        ACC(e2.x, 8)  ACC(e2.y, 9)  ACC(e2.z, 10) ACC(e2.w, 11)
        ACC(e3.x, 12) ACC(e3.y, 13) ACC(e3.z, 14) ACC(e3.w, 15)
        #undef ACC
        const float s = bet * vms[wv * 16 + i];
        const float2 zraw = zr[15 + i];
        float2 hv;
        hv.x = fmaf(s, px, zraw.x);
        hv.y = fmaf(s, py, zraw.y);
        const int t = tsub + i;
        *(float2*)(out + (((size_t)b * NT + t) * NM + m) * ND + lane * 2) = hv;
    }
}

extern "C" void kernel_launch(void* const* d_in, const int* in_sizes, int n_in,
                              void* d_out, int out_size, void* d_ws, size_t ws_size,
                              hipStream_t stream) {
    const float* z    = (const float*)d_in[0];
    const float* vm   = (const float*)d_in[1];
    const float* gw1  = (const float*)d_in[2];
    const float* gb1  = (const float*)d_in[3];
    const float* gw2  = (const float*)d_in[4];
    const float* gb2  = (const float*)d_in[5];
    const float* beta = (const float*)d_in[6];
    float* out = (float*)d_out;

    float* wsf = (float*)d_ws;
    float* Kf  = wsf;         // 256 floats
    float* za  = wsf + 256;   // B*M*T = 32768 floats

    rama_init_k<<<1, 64, 0, stream>>>(Kf);
    rama_reduce_k<<<(NB * NT * NM) / 4, 256, 0, stream>>>(z, vm, za);
    rama_fuse_k<<<NB * NM * (NT / 64), 256, 0, stream>>>(
        z, vm, gw1, gb1, gw2, gb2, beta, Kf, za, out);
}

// Round 2
// 39.944 us; speedup vs baseline: 2.3663x; 2.3663x over previous
//
#include <hip/hip_runtime.h>
#include <math.h>

#define NB 8
#define NT 512
#define NM 8
#define ND 128
#define NQ 16
#define NW 16

// Integer Ramanujan sums c_q(n) = mu(q/g)*phi(q)/phi(q/g), g=gcd(n,q),
// for q=1..16 (rows), n=0..15 (cols). Exact values (cos-sum is integer).
__device__ __constant__ short RAMA_C[256] = {
    // q=1
    1,1,1,1,1,1,1,1,1,1,1,1,1,1,1,1,
    // q=2
    1,-1,1,-1,1,-1,1,-1,1,-1,1,-1,1,-1,1,-1,
    // q=3
    2,-1,-1,2,-1,-1,2,-1,-1,2,-1,-1,2,-1,-1,2,
    // q=4
    2,0,-2,0,2,0,-2,0,2,0,-2,0,2,0,-2,0,
    // q=5
    4,-1,-1,-1,-1,4,-1,-1,-1,-1,4,-1,-1,-1,-1,4,
    // q=6
    2,1,-1,-2,-1,1,2,1,-1,-2,-1,1,2,1,-1,-2,
    // q=7
    6,-1,-1,-1,-1,-1,-1,6,-1,-1,-1,-1,-1,-1,6,-1,
    // q=8
    4,0,0,0,-4,0,0,0,4,0,0,0,-4,0,0,0,
    // q=9
    6,0,0,-3,0,0,-3,0,0,6,0,0,-3,0,0,-3,
    // q=10
    4,1,-1,1,-1,-4,-1,1,-1,1,4,1,-1,1,-1,-4,
    // q=11
    10,-1,-1,-1,-1,-1,-1,-1,-1,-1,-1,10,-1,-1,-1,-1,
    // q=12
    4,0,2,0,-2,0,-4,0,-2,0,2,0,4,0,2,0,
    // q=13
    12,-1,-1,-1,-1,-1,-1,-1,-1,-1,-1,-1,-1,12,-1,-1,
    // q=14
    6,1,-1,1,-1,1,-1,-6,-1,1,-1,1,-1,1,6,1,
    // q=15
    8,1,1,-2,1,-4,-2,1,1,-2,-4,1,-2,1,1,8,
    // q=16
    8,0,0,0,0,0,0,0,-8,0,0,0,0,0,0,0
};

// ---------------- kernel 1: z_anl[b,m,t] = mean_d z[b,t,m,d] * vm[b,t,m] ----------------
__global__ __launch_bounds__(256) void rama_reduce_k(
    const float* __restrict__ z, const float* __restrict__ vm,
    float* __restrict__ za)
{
    const int row  = blockIdx.x * 4 + (threadIdx.x >> 6);   // (b*T+t)*M + m
    const int lane = threadIdx.x & 63;
    const float2 v = *(const float2*)(z + (size_t)row * ND + lane * 2);
    float s = v.x + v.y;
    #pragma unroll
    for (int off = 32; off; off >>= 1) s += __shfl_xor(s, off, 64);
    if (lane == 0) {
        const int m = row & 7;
        const int t = (row >> 3) & 511;
        const int b = row >> 12;
        za[(b * NM + m) * NT + t] = (s * (1.0f / 128.0f)) * vm[row];
    }
}

// ---------------- kernel 2: fused gate + synthesis ----------------
__global__ __launch_bounds__(256) void rama_fuse_k(
    const float* __restrict__ z, const float* __restrict__ vm,
    const float* __restrict__ gw1, const float* __restrict__ gb1,
    const float* __restrict__ gw2, const float* __restrict__ gb2,
    const float* __restrict__ beta,
    const float* __restrict__ za,
    float* __restrict__ out)
{
    __shared__ __align__(16) float Ks[256];
    __shared__ __align__(16) float effs[64][16];
    __shared__ float vms[64];

    const int tid   = threadIdx.x;
    const int blk   = blockIdx.x;
    const int chunk = blk & 7;          // T/64 = 8
    const int m     = (blk >> 3) & 7;
    const int b     = blk >> 6;
    const int t0    = chunk * 64;

    // compute normalized FIR bank in-block from the integer table
    {
        const int q = tid >> 4;
        float sum = 0.0f, ss = 0.0f;
        #pragma unroll
        for (int j = 0; j < 16; ++j) sum += (float)RAMA_C[q * 16 + j];
        const float mean = sum * (1.0f / 16.0f);
        #pragma unroll
        for (int j = 0; j < 16; ++j) {
            const float d = (float)RAMA_C[q * 16 + j] - mean;
            ss += d * d;
        }
        const float denom = sqrtf(fmaxf(ss, 1e-6f));
        Ks[tid] = ((float)RAMA_C[tid] - mean) / denom;
    }
    __syncthreads();

    // ---- issue global loads for phase B early (overlap with gate compute) ----
    const int wv   = tid >> 6;
    const int lane = tid & 63;
    const int tsub = t0 + wv * 16;
    float2 zr[31];
    #pragma unroll
    for (int j = 0; j < 31; ++j) {
        const int t = tsub - 15 + j;
        if (t >= 0) {
            zr[j] = *(const float2*)(z + (((size_t)b * NT + t) * NM + m) * ND + lane * 2);
        } else { zr[j].x = 0.0f; zr[j].y = 0.0f; }
    }

    // ---- phase A: gates for 64 timesteps (wave 0) ----
    if (tid < 64) {
        const int t = t0 + tid;
        const float* zab = za + b * (NM * NT);
        float rg[16];
        #pragma unroll
        for (int m2 = 0; m2 < 8; ++m2) {
            float zwl[16];
            #pragma unroll
            for (int dly = 0; dly < 16; ++dly) {
                const int tt = t - dly;
                zwl[dly] = (tt >= 0) ? zab[m2 * NT + tt] : 0.0f;
            }
            #pragma unroll
            for (int h = 0; h < 2; ++h) {
                const float* kr = &Ks[(2 * m + h) * 16];
                float acc = 0.0f;
                #pragma unroll
                for (int dly = 0; dly < 16; ++dly)
                    acc = fmaf(kr[15 - dly], zwl[dly], acc);
                rg[h * 8 + m2] = acc;   // q' = h*8 + m2 (scramble mapping)
            }
        }
        float h1[16];
        #pragma unroll
        for (int q = 0; q < 16; ++q) {
            const float v = fmaf(rg[q], gw1[q], gb1[q]);
            h1[q] = 0.5f * v * (1.0f + erff(v * 0.70710678118654752440f));
        }
        float g[16];
        #pragma unroll
        for (int p = 0; p < 16; ++p) {
            float acc = gb2[p];
            #pragma unroll
            for (int q = 0; q < 16; ++q) acc = fmaf(h1[q], gw2[p * 16 + q], acc);
            g[p] = 1.0f / (1.0f + expf(-acc));
        }
        float eff16[16];
        #pragma unroll
        for (int dly = 0; dly < 16; ++dly) {
            float acc = 0.0f;
            #pragma unroll
            for (int p = 0; p < 16; ++p) acc = fmaf(Ks[p * 16 + 15 - dly], g[p], acc);
            const int tt = t - dly;
            const float v = (tt >= 0) ? vm[((size_t)b * NT + tt) * NM + m] : 0.0f;
            eff16[dly] = acc * v;       // fold mask into taps
        }
        float4* er = (float4*)&effs[tid][0];
        er[0] = make_float4(eff16[0],  eff16[1],  eff16[2],  eff16[3]);
        er[1] = make_float4(eff16[4],  eff16[5],  eff16[6],  eff16[7]);
        er[2] = make_float4(eff16[8],  eff16[9],  eff16[10], eff16[11]);
        er[3] = make_float4(eff16[12], eff16[13], eff16[14], eff16[15]);
        vms[tid] = vm[((size_t)b * NT + t) * NM + m];
    }
    __syncthreads();

    // ---- phase B: 16-tap synthesis, each wave does 16 timesteps x 128 d ----
    const float bet = beta[0];
    #pragma unroll
    for (int i = 0; i < 16; ++i) {
        const float* erow = &effs[wv * 16 + i][0];
        const float4 e0 = *(const float4*)(erow + 0);
        const float4 e1 = *(const float4*)(erow + 4);
        const float4 e2 = *(const float4*)(erow + 8);
        const float4 e3 = *(const float4*)(erow + 12);
        float px = 0.0f, py = 0.0f;
        #define ACC(EV, DLY) { const float2 zv = zr[15 + i - (DLY)]; \
                               px = fmaf((EV), zv.x, px); py = fmaf((EV), zv.y, py); }
        ACC(e0.x, 0)  ACC(e0.y, 1)  ACC(e0.z, 2)  ACC(e0.w, 3)
        ACC(e1.x, 4)  ACC(e1.y, 5)  ACC(e1.z, 6)  ACC(e1.w, 7)
        ACC(e2.x, 8)  ACC(e2.y, 9)  ACC(e2.z, 10) ACC(e2.w, 11)
        ACC(e3.x, 12) ACC(e3.y, 13) ACC(e3.z, 14) ACC(e3.w, 15)
        #undef ACC
        const float s = bet * vms[wv * 16 + i];
        const float2 zraw = zr[15 + i];
        float2 hv;
        hv.x = fmaf(s, px, zraw.x);
        hv.y = fmaf(s, py, zraw.y);
        const int t = tsub + i;
        *(float2*)(out + (((size_t)b * NT + t) * NM + m) * ND + lane * 2) = hv;
    }
}

extern "C" void kernel_launch(void* const* d_in, const int* in_sizes, int n_in,
                              void* d_out, int out_size, void* d_ws, size_t ws_size,
                              hipStream_t stream) {
    const float* z    = (const float*)d_in[0];
    const float* vm   = (const float*)d_in[1];
    const float* gw1  = (const float*)d_in[2];
    const float* gb1  = (const float*)d_in[3];
    const float* gw2  = (const float*)d_in[4];
    const float* gb2  = (const float*)d_in[5];
    const float* beta = (const float*)d_in[6];
    float* out = (float*)d_out;

    float* za = (float*)d_ws;   // B*M*T = 32768 floats

    rama_reduce_k<<<(NB * NT * NM) / 4, 256, 0, stream>>>(z, vm, za);
    rama_fuse_k<<<NB * NM * (NT / 64), 256, 0, stream>>>(
        z, vm, gw1, gb1, gw2, gb2, beta, za, out);
}

// Round 3
// 35.494 us; speedup vs baseline: 2.6629x; 1.1254x over previous
//
#include <hip/hip_runtime.h>
#include <math.h>

#define NB 8
#define NT 512
#define NM 8
#define ND 128

// Integer Ramanujan sums c_q(n) = mu(q/g)*phi(q)/phi(q/g), g=gcd(n,q),
// for q=1..16 (rows), n=0..15 (cols). Exact values (cos-sum is integer).
__device__ __constant__ short RAMA_C[256] = {
    1,1,1,1,1,1,1,1,1,1,1,1,1,1,1,1,
    1,-1,1,-1,1,-1,1,-1,1,-1,1,-1,1,-1,1,-1,
    2,-1,-1,2,-1,-1,2,-1,-1,2,-1,-1,2,-1,-1,2,
    2,0,-2,0,2,0,-2,0,2,0,-2,0,2,0,-2,0,
    4,-1,-1,-1,-1,4,-1,-1,-1,-1,4,-1,-1,-1,-1,4,
    2,1,-1,-2,-1,1,2,1,-1,-2,-1,1,2,1,-1,-2,
    6,-1,-1,-1,-1,-1,-1,6,-1,-1,-1,-1,-1,-1,6,-1,
    4,0,0,0,-4,0,0,0,4,0,0,0,-4,0,0,0,
    6,0,0,-3,0,0,-3,0,0,6,0,0,-3,0,0,-3,
    4,1,-1,1,-1,-4,-1,1,-1,1,4,1,-1,1,-1,-4,
    10,-1,-1,-1,-1,-1,-1,-1,-1,-1,-1,10,-1,-1,-1,-1,
    4,0,2,0,-2,0,-4,0,-2,0,2,0,4,0,2,0,
    12,-1,-1,-1,-1,-1,-1,-1,-1,-1,-1,-1,-1,12,-1,-1,
    6,1,-1,1,-1,1,-1,-6,-1,1,-1,1,-1,1,6,1,
    8,1,1,-2,1,-4,-2,1,1,-2,-4,1,-2,1,1,8,
    8,0,0,0,0,0,0,0,-8,0,0,0,0,0,0,0
};

// ---- kernel 1: za[b][t][m] = mean_d z[b,t,m,d] * vm[b,t,m]  (row = (b*T+t)*M+m) ----
__global__ __launch_bounds__(256) void rama_reduce_k(
    const float* __restrict__ z, const float* __restrict__ vm,
    float* __restrict__ za)
{
    const int row = blockIdx.x * 8 + (threadIdx.x >> 5);
    const int l   = threadIdx.x & 31;
    const float4 v = *(const float4*)(z + (size_t)row * ND + l * 4);
    float s = (v.x + v.y) + (v.z + v.w);
    #pragma unroll
    for (int off = 16; off; off >>= 1) s += __shfl_xor(s, off, 32);
    if (l == 0) za[row] = s * (1.0f / 128.0f) * vm[row];
}

// ---- kernel 2: fused gate + synthesis ----
__global__ __launch_bounds__(256) void rama_fuse_k(
    const float* __restrict__ z, const float* __restrict__ vm,
    const float* __restrict__ gw1, const float* __restrict__ gb1,
    const float* __restrict__ gw2, const float* __restrict__ gb2,
    const float* __restrict__ beta,
    const float* __restrict__ za,
    float* __restrict__ out)
{
    __shared__ __align__(16) float Ks[256];
    __shared__ __align__(16) float effs[64][20];   // padded row: conflict-free writes
    __shared__ float vms[64];

    const int tid   = threadIdx.x;
    const int blk   = blockIdx.x;
    const int chunk = blk & 7;          // T/64 = 8
    const int m     = (blk >> 3) & 7;
    const int b     = blk >> 6;
    const int t0    = chunk * 64;
    const int wv    = tid >> 6;
    const int lane  = tid & 63;
    const int tw    = t0 + wv * 16;     // this wave's 16-timestep strip

    // normalized FIR bank from the integer table
    {
        const int q = tid >> 4;
        float sum = 0.0f, ss = 0.0f;
        #pragma unroll
        for (int j = 0; j < 16; ++j) sum += (float)RAMA_C[q * 16 + j];
        const float mean = sum * (1.0f / 16.0f);
        #pragma unroll
        for (int j = 0; j < 16; ++j) {
            const float d = (float)RAMA_C[q * 16 + j] - mean;
            ss += d * d;
        }
        Ks[tid] = ((float)RAMA_C[tid] - mean) / sqrtf(fmaxf(ss, 1e-6f));
    }
    __syncthreads();   // only barrier: Ks visible to all waves

    // ---- phase A: each wave's lanes<16 compute gates for its own 16 t ----
    if (lane < 16) {
        const int t = tw + lane;
        const float4* za4 = (const float4*)za + (size_t)b * NT * 2;  // [t][2]
        const float k0b = 0.0f; (void)k0b;
        float rg[16];
        #pragma unroll
        for (int q = 0; q < 16; ++q) rg[q] = 0.0f;
        #pragma unroll
        for (int dly = 0; dly < 16; ++dly) {
            const int tt = t - dly;
            float4 lo, hi;
            if (tt >= 0) { lo = za4[tt * 2]; hi = za4[tt * 2 + 1]; }
            else { lo = make_float4(0,0,0,0); hi = make_float4(0,0,0,0); }
            const float k0 = Ks[(2 * m)     * 16 + 15 - dly];
            const float k1 = Ks[(2 * m + 1) * 16 + 15 - dly];
            float zw[8];
            zw[0]=lo.x; zw[1]=lo.y; zw[2]=lo.z; zw[3]=lo.w;
            zw[4]=hi.x; zw[5]=hi.y; zw[6]=hi.z; zw[7]=hi.w;
            #pragma unroll
            for (int m2 = 0; m2 < 8; ++m2) {
                rg[m2]     = fmaf(k0, zw[m2], rg[m2]);     // q' = 0*8+m2
                rg[8 + m2] = fmaf(k1, zw[m2], rg[8 + m2]); // q' = 1*8+m2
            }
        }
        float h1[16];
        #pragma unroll
        for (int q = 0; q < 16; ++q) {
            const float v = fmaf(rg[q], gw1[q], gb1[q]);
            h1[q] = 0.5f * v * (1.0f + erff(v * 0.70710678118654752440f));
        }
        float g[16];
        #pragma unroll
        for (int p = 0; p < 16; ++p) {
            float acc = gb2[p];
            #pragma unroll
            for (int q = 0; q < 16; ++q) acc = fmaf(h1[q], gw2[p * 16 + q], acc);
            g[p] = 1.0f / (1.0f + expf(-acc));
        }
        float eff16[16];
        #pragma unroll
        for (int dly = 0; dly < 16; ++dly) {
            float acc = 0.0f;
            #pragma unroll
            for (int p = 0; p < 16; ++p) acc = fmaf(Ks[p * 16 + 15 - dly], g[p], acc);
            const int tt = t - dly;
            const float v = (tt >= 0) ? vm[((size_t)b * NT + tt) * NM + m] : 0.0f;
            eff16[dly] = acc * v;   // fold mask into taps
        }
        const int er = wv * 16 + lane;
        float4* ep = (float4*)&effs[er][0];
        ep[0] = make_float4(eff16[0],  eff16[1],  eff16[2],  eff16[3]);
        ep[1] = make_float4(eff16[4],  eff16[5],  eff16[6],  eff16[7]);
        ep[2] = make_float4(eff16[8],  eff16[9],  eff16[10], eff16[11]);
        ep[3] = make_float4(eff16[12], eff16[13], eff16[14], eff16[15]);
        vms[er] = vm[((size_t)b * NT + t) * NM + m];
    }
    // No __syncthreads needed: each wave reads only the effs rows it wrote.
    __builtin_amdgcn_sched_barrier(0);   // keep zr loads AFTER phase A (VGPR pressure)

    // ---- load this wave's z window (after gate regs are dead) ----
    float2 zr[31];
    #pragma unroll
    for (int j = 0; j < 31; ++j) {
        const int t = tw - 15 + j;
        if (t >= 0) {
            zr[j] = *(const float2*)(z + (((size_t)b * NT + t) * NM + m) * ND + lane * 2);
        } else { zr[j].x = 0.0f; zr[j].y = 0.0f; }
    }

    // ---- phase B: 16-tap synthesis, 16 timesteps x 128 d per wave ----
    const float bet = beta[0];
    #pragma unroll
    for (int i = 0; i < 16; ++i) {
        const float* erow = &effs[wv * 16 + i][0];
        const float4 e0 = *(const float4*)(erow + 0);
        const float4 e1 = *(const float4*)(erow + 4);
        const float4 e2 = *(const float4*)(erow + 8);
        const float4 e3 = *(const float4*)(erow + 12);
        float px = 0.0f, py = 0.0f;
        #define ACC(EV, DLY) { const float2 zv = zr[15 + i - (DLY)]; \
                               px = fmaf((EV), zv.x, px); py = fmaf((EV), zv.y, py); }
        ACC(e0.x, 0)  ACC(e0.y, 1)  ACC(e0.z, 2)  ACC(e0.w, 3)
        ACC(e1.x, 4)  ACC(e1.y, 5)  ACC(e1.z, 6)  ACC(e1.w, 7)
        ACC(e2.x, 8)  ACC(e2.y, 9)  ACC(e2.z, 10) ACC(e2.w, 11)
        ACC(e3.x, 12) ACC(e3.y, 13) ACC(e3.z, 14) ACC(e3.w, 15)
        #undef ACC
        const float s = bet * vms[wv * 16 + i];
        const float2 zraw = zr[15 + i];
        float2 hv;
        hv.x = fmaf(s, px, zraw.x);
        hv.y = fmaf(s, py, zraw.y);
        const int t = tw + i;
        *(float2*)(out + (((size_t)b * NT + t) * NM + m) * ND + lane * 2) = hv;
    }
}

extern "C" void kernel_launch(void* const* d_in, const int* in_sizes, int n_in,
                              void* d_out, int out_size, void* d_ws, size_t ws_size,
                              hipStream_t stream) {
    const float* z    = (const float*)d_in[0];
    const float* vm   = (const float*)d_in[1];
    const float* gw1  = (const float*)d_in[2];
    const float* gb1  = (const float*)d_in[3];
    const float* gw2  = (const float*)d_in[4];
    const float* gb2  = (const float*)d_in[5];
    const float* beta = (const float*)d_in[6];
    float* out = (float*)d_out;

    float* za = (float*)d_ws;   // [B][T][M] = 32768 floats

    rama_reduce_k<<<(NB * NT * NM) / 8, 256, 0, stream>>>(z, vm, za);
    rama_fuse_k<<<NB * NM * (NT / 64), 256, 0, stream>>>(
        z, vm, gw1, gb1, gw2, gb2, beta, za, out);
}

// Round 4
// 28.445 us; speedup vs baseline: 3.3228x; 1.2478x over previous
//
#include <hip/hip_runtime.h>
#include <math.h>

#define NB 8
#define NT 512
#define NM 8
#define ND 128

// Integer Ramanujan sums c_q(n) = mu(q/g)*phi(q)/phi(q/g), g=gcd(n,q),
// q=1..16 (rows), n=0..15 (cols). Exact (the cos-sum is integer-valued).
__device__ __constant__ short RAMA_C[256] = {
    1,1,1,1,1,1,1,1,1,1,1,1,1,1,1,1,
    1,-1,1,-1,1,-1,1,-1,1,-1,1,-1,1,-1,1,-1,
    2,-1,-1,2,-1,-1,2,-1,-1,2,-1,-1,2,-1,-1,2,
    2,0,-2,0,2,0,-2,0,2,0,-2,0,2,0,-2,0,
    4,-1,-1,-1,-1,4,-1,-1,-1,-1,4,-1,-1,-1,-1,4,
    2,1,-1,-2,-1,1,2,1,-1,-2,-1,1,2,1,-1,-2,
    6,-1,-1,-1,-1,-1,-1,6,-1,-1,-1,-1,-1,-1,6,-1,
    4,0,0,0,-4,0,0,0,4,0,0,0,-4,0,0,0,
    6,0,0,-3,0,0,-3,0,0,6,0,0,-3,0,0,-3,
    4,1,-1,1,-1,-4,-1,1,-1,1,4,1,-1,1,-1,-4,
    10,-1,-1,-1,-1,-1,-1,-1,-1,-1,-1,10,-1,-1,-1,-1,
    4,0,2,0,-2,0,-4,0,-2,0,2,0,4,0,2,0,
    12,-1,-1,-1,-1,-1,-1,-1,-1,-1,-1,-1,-1,12,-1,-1,
    6,1,-1,1,-1,1,-1,-6,-1,1,-1,1,-1,1,6,1,
    8,1,1,-2,1,-4,-2,1,1,-2,-4,1,-2,1,1,8,
    8,0,0,0,0,0,0,0,-8,0,0,0,0,0,0,0
};

// ---- K1: za[b][t][m] = mean_d z[b,t,m,d] * vm[b,t,m] ----
__global__ __launch_bounds__(256) void rama_reduce_k(
    const float* __restrict__ z, const float* __restrict__ vm,
    float* __restrict__ za)
{
    const int row = blockIdx.x * 8 + (threadIdx.x >> 5);   // (b*T+t)*M + m
    const int l   = threadIdx.x & 31;
    const float4 v = *(const float4*)(z + (size_t)row * ND + l * 4);
    float s = (v.x + v.y) + (v.z + v.w);
    #pragma unroll
    for (int off = 16; off; off >>= 1) s += __shfl_xor(s, off, 32);
    if (l == 0) za[row] = s * (1.0f / 128.0f) * vm[row];
}

// ---- K2: eff[(b*M+m)*T+t][16] with beta, vm[t] and vm[t-dly] folded in ----
__global__ __launch_bounds__(64) void rama_gate_k(
    const float* __restrict__ vm,
    const float* __restrict__ gw1, const float* __restrict__ gb1,
    const float* __restrict__ gw2, const float* __restrict__ gb2,
    const float* __restrict__ beta,
    const float* __restrict__ za,
    float* __restrict__ eff)
{
    __shared__ float Ks[256];
    const int tid = threadIdx.x;

    if (tid < 16) {
        const int q = tid;
        float sum = 0.0f, ss = 0.0f;
        #pragma unroll
        for (int j = 0; j < 16; ++j) sum += (float)RAMA_C[q * 16 + j];
        const float mean = sum * (1.0f / 16.0f);
        #pragma unroll
        for (int j = 0; j < 16; ++j) {
            const float d = (float)RAMA_C[q * 16 + j] - mean;
            ss += d * d;
        }
        const float denom = sqrtf(fmaxf(ss, 1e-6f));
        #pragma unroll
        for (int j = 0; j < 16; ++j)
            Ks[q * 16 + j] = ((float)RAMA_C[q * 16 + j] - mean) / denom;
    }
    __syncthreads();

    const int blk   = blockIdx.x;
    const int chunk = blk & 7;          // 8 chunks of 64 t
    const int m     = (blk >> 3) & 7;
    const int b     = blk >> 6;
    const int t     = chunk * 64 + tid;

    const float4* za4 = (const float4*)za + (size_t)b * NT * 2;  // [t][2]

    float rg[16];
    #pragma unroll
    for (int q = 0; q < 16; ++q) rg[q] = 0.0f;
    #pragma unroll
    for (int dly = 0; dly < 16; ++dly) {
        const int tt = t - dly;
        float4 lo, hi;
        if (tt >= 0) { lo = za4[tt * 2]; hi = za4[tt * 2 + 1]; }
        else { lo = make_float4(0,0,0,0); hi = make_float4(0,0,0,0); }
        const float k0 = Ks[(2 * m)     * 16 + 15 - dly];
        const float k1 = Ks[(2 * m + 1) * 16 + 15 - dly];
        float zw[8];
        zw[0]=lo.x; zw[1]=lo.y; zw[2]=lo.z; zw[3]=lo.w;
        zw[4]=hi.x; zw[5]=hi.y; zw[6]=hi.z; zw[7]=hi.w;
        #pragma unroll
        for (int m2 = 0; m2 < 8; ++m2) {
            rg[m2]     = fmaf(k0, zw[m2], rg[m2]);     // q' = 0*8+m2
            rg[8 + m2] = fmaf(k1, zw[m2], rg[8 + m2]); // q' = 1*8+m2
        }
    }
    float h1[16];
    #pragma unroll
    for (int q = 0; q < 16; ++q) {
        const float v = fmaf(rg[q], gw1[q], gb1[q]);
        h1[q] = 0.5f * v * (1.0f + erff(v * 0.70710678118654752440f));
    }
    float g[16];
    #pragma unroll
    for (int p = 0; p < 16; ++p) {
        float acc = gb2[p];
        #pragma unroll
        for (int q = 0; q < 16; ++q) acc = fmaf(h1[q], gw2[p * 16 + q], acc);
        g[p] = 1.0f / (1.0f + expf(-acc));
    }
    // fold beta * vm[t] (output mask) and vm[t-dly] (input mask) into taps
    const float sc = beta[0] * vm[((size_t)b * NT + t) * NM + m];
    float eff16[16];
    #pragma unroll
    for (int dly = 0; dly < 16; ++dly) {
        float acc = 0.0f;
        #pragma unroll
        for (int p = 0; p < 16; ++p) acc = fmaf(Ks[p * 16 + 15 - dly], g[p], acc);
        const int tt = t - dly;
        const float v = (tt >= 0) ? vm[((size_t)b * NT + tt) * NM + m] : 0.0f;
        eff16[dly] = acc * v * sc;
    }
    float4* ep = (float4*)(eff + ((size_t)((b * NM + m) * NT + t)) * 16);
    ep[0] = make_float4(eff16[0],  eff16[1],  eff16[2],  eff16[3]);
    ep[1] = make_float4(eff16[4],  eff16[5],  eff16[6],  eff16[7]);
    ep[2] = make_float4(eff16[8],  eff16[9],  eff16[10], eff16[11]);
    ep[3] = make_float4(eff16[12], eff16[13], eff16[14], eff16[15]);
}

// ---- K3: out[b,t,m,:] = z + sum_dly eff[b,m,t,dly] * z[b,t-dly,m,:] ----
__global__ __launch_bounds__(256) void rama_syn_k(
    const float* __restrict__ z, const float* __restrict__ eff,
    float* __restrict__ out)
{
    __shared__ __align__(16) float4 effs[32][4];   // 32 t x 16 taps

    const int tid   = threadIdx.x;
    const int blk   = blockIdx.x;
    const int chunk = blk & 15;         // 16 chunks of 32 t
    const int m     = (blk >> 4) & 7;
    const int b     = blk >> 7;
    const int t0    = chunk * 32;
    const int wv    = tid >> 6;
    const int lane  = tid & 63;
    const int tw    = t0 + wv * 8;      // this wave's 8-timestep strip

    // stage eff tile (2 KB) into LDS
    if (tid < 128) {
        ((float4*)effs)[tid] =
            ((const float4*)(eff + ((size_t)((b * NM + m) * NT + t0)) * 16))[tid];
    }

    // this wave's z window: 23 x float2 per lane, all independent loads
    float2 zr[23];
    #pragma unroll
    for (int j = 0; j < 23; ++j) {
        const int t = tw - 15 + j;
        if (t >= 0) {
            zr[j] = *(const float2*)(z + (((size_t)b * NT + t) * NM + m) * ND + lane * 2);
        } else { zr[j].x = 0.0f; zr[j].y = 0.0f; }
    }
    __syncthreads();

    #pragma unroll
    for (int i = 0; i < 8; ++i) {
        const float4 e0 = effs[wv * 8 + i][0];
        const float4 e1 = effs[wv * 8 + i][1];
        const float4 e2 = effs[wv * 8 + i][2];
        const float4 e3 = effs[wv * 8 + i][3];
        float px = 0.0f, py = 0.0f;
        #define ACC(EV, DLY) { const float2 zv = zr[15 + i - (DLY)]; \
                               px = fmaf((EV), zv.x, px); py = fmaf((EV), zv.y, py); }
        ACC(e0.x, 0)  ACC(e0.y, 1)  ACC(e0.z, 2)  ACC(e0.w, 3)
        ACC(e1.x, 4)  ACC(e1.y, 5)  ACC(e1.z, 6)  ACC(e1.w, 7)
        ACC(e2.x, 8)  ACC(e2.y, 9)  ACC(e2.z, 10) ACC(e2.w, 11)
        ACC(e3.x, 12) ACC(e3.y, 13) ACC(e3.z, 14) ACC(e3.w, 15)
        #undef ACC
        const float2 zraw = zr[15 + i];
        float2 hv;
        hv.x = zraw.x + px;             // beta & masks already folded into eff
        hv.y = zraw.y + py;
        const int t = tw + i;
        *(float2*)(out + (((size_t)b * NT + t) * NM + m) * ND + lane * 2) = hv;
    }
}

extern "C" void kernel_launch(void* const* d_in, const int* in_sizes, int n_in,
                              void* d_out, int out_size, void* d_ws, size_t ws_size,
                              hipStream_t stream) {
    const float* z    = (const float*)d_in[0];
    const float* vm   = (const float*)d_in[1];
    const float* gw1  = (const float*)d_in[2];
    const float* gb1  = (const float*)d_in[3];
    const float* gw2  = (const float*)d_in[4];
    const float* gb2  = (const float*)d_in[5];
    const float* beta = (const float*)d_in[6];
    float* out = (float*)d_out;

    float* za  = (float*)d_ws;            // [B][T][M]            = 32768 floats
    float* eff = (float*)d_ws + 32768;    // [B][M][T][16]        = 524288 floats

    rama_reduce_k<<<(NB * NT * NM) / 8, 256, 0, stream>>>(z, vm, za);
    rama_gate_k<<<NB * NM * (NT / 64), 64, 0, stream>>>(
        vm, gw1, gb1, gw2, gb2, beta, za, eff);
    rama_syn_k<<<NB * NM * (NT / 32), 256, 0, stream>>>(z, eff, out);
}

// Round 5
// 28.249 us; speedup vs baseline: 3.3459x; 1.0069x over previous
//
#include <hip/hip_runtime.h>
#include <math.h>

#define NB 8
#define NT 512
#define NM 8
#define ND 128
#define TC 16   // timesteps per block

// Integer Ramanujan sums c_q(n) = mu(q/g)*phi(q)/phi(q/g), g=gcd(n,q),
// q=1..16 (rows), n=0..15 (cols). Exact (the cos-sum is integer-valued).
__device__ __constant__ short RAMA_C[256] = {
    1,1,1,1,1,1,1,1,1,1,1,1,1,1,1,1,
    1,-1,1,-1,1,-1,1,-1,1,-1,1,-1,1,-1,1,-1,
    2,-1,-1,2,-1,-1,2,-1,-1,2,-1,-1,2,-1,-1,2,
    2,0,-2,0,2,0,-2,0,2,0,-2,0,2,0,-2,0,
    4,-1,-1,-1,-1,4,-1,-1,-1,-1,4,-1,-1,-1,-1,4,
    2,1,-1,-2,-1,1,2,1,-1,-2,-1,1,2,1,-1,-2,
    6,-1,-1,-1,-1,-1,-1,6,-1,-1,-1,-1,-1,-1,6,-1,
    4,0,0,0,-4,0,0,0,4,0,0,0,-4,0,0,0,
    6,0,0,-3,0,0,-3,0,0,6,0,0,-3,0,0,-3,
    4,1,-1,1,-1,-4,-1,1,-1,1,4,1,-1,1,-1,-4,
    10,-1,-1,-1,-1,-1,-1,-1,-1,-1,-1,10,-1,-1,-1,-1,
    4,0,2,0,-2,0,-4,0,-2,0,2,0,4,0,2,0,
    12,-1,-1,-1,-1,-1,-1,-1,-1,-1,-1,-1,-1,12,-1,-1,
    6,1,-1,1,-1,1,-1,-6,-1,1,-1,1,-1,1,6,1,
    8,1,1,-2,1,-4,-2,1,1,-2,-4,1,-2,1,1,8,
    8,0,0,0,0,0,0,0,-8,0,0,0,0,0,0,0
};

__global__ __launch_bounds__(512, 1) void rama_one_k(
    const float* __restrict__ z, const float* __restrict__ vm,
    const float* __restrict__ gw1, const float* __restrict__ gb1,
    const float* __restrict__ gw2, const float* __restrict__ gb2,
    const float* __restrict__ beta,
    float* __restrict__ out)
{
    __shared__ float Ks[256];
    __shared__ float za_s[31][9];                 // padded: conflict-free gate reads
    __shared__ float vm_s[31][9];
    __shared__ __align__(16) float effs[8][16][16];

    const int tid  = threadIdx.x;
    const int wv   = tid >> 6;       // wave 0..7  == m for reduce/synthesis
    const int lane = tid & 63;
    const int blk  = blockIdx.x;
    const int tc   = blk & 31;       // 32 chunks of 16 t
    const int b    = blk >> 5;
    const int t0   = tc * TC;
    const int m    = wv;

    // --- normalized FIR bank from integer table (threads 0..255) ---
    if (tid < 256) {
        const int q = tid >> 4;
        float sum = 0.0f, ss = 0.0f;
        #pragma unroll
        for (int j = 0; j < 16; ++j) sum += (float)RAMA_C[q * 16 + j];
        const float mean = sum * (1.0f / 16.0f);
        #pragma unroll
        for (int j = 0; j < 16; ++j) {
            const float d = (float)RAMA_C[q * 16 + j] - mean;
            ss += d * d;
        }
        Ks[tid] = ((float)RAMA_C[tid] - mean) / sqrtf(fmaxf(ss, 1e-6f));
    }

    // --- phase 1: wave w loads its 31-row z window ONCE; reduce rows -> za_s ---
    if (lane < 31) {
        const int tt = t0 - 15 + lane;
        vm_s[lane][m] = (tt >= 0) ? vm[((size_t)b * NT + tt) * NM + m] : 0.0f;
    }
    float2 zr[31];
    #pragma unroll
    for (int j = 0; j < 31; ++j) {
        const int tt = t0 - 15 + j;
        if (tt >= 0) {
            zr[j] = *(const float2*)(z + (((size_t)b * NT + tt) * NM + m) * ND + lane * 2);
        } else { zr[j].x = 0.0f; zr[j].y = 0.0f; }
    }
    #pragma unroll
    for (int j = 0; j < 31; ++j) {
        float s = zr[j].x + zr[j].y;
        #pragma unroll
        for (int off = 32; off; off >>= 1) s += __shfl_xor(s, off, 64);
        if (lane == 0) za_s[j][m] = s * (1.0f / 128.0f) * vm_s[j][m];
    }
    __syncthreads();   // za_s, vm_s, Ks visible

    // --- phase 2: 128 gate threads (waves 0-1, fully packed) ---
    if (tid < 128) {
        const int gm = tid >> 4;     // filter/channel m
        const int gi = tid & 15;     // t = t0 + gi
        float rg[16];
        #pragma unroll
        for (int q = 0; q < 16; ++q) rg[q] = 0.0f;
        #pragma unroll
        for (int dly = 0; dly < 16; ++dly) {
            const int j  = gi + 15 - dly;
            const float k0 = Ks[(2 * gm)     * 16 + 15 - dly];
            const float k1 = Ks[(2 * gm + 1) * 16 + 15 - dly];
            #pragma unroll
            for (int m2 = 0; m2 < 8; ++m2) {
                const float zv = za_s[j][m2];
                rg[m2]     = fmaf(k0, zv, rg[m2]);     // q' = 0*8+m2
                rg[8 + m2] = fmaf(k1, zv, rg[8 + m2]); // q' = 1*8+m2
            }
        }
        float h1[16];
        #pragma unroll
        for (int q = 0; q < 16; ++q) {
            const float v = fmaf(rg[q], gw1[q], gb1[q]);
            h1[q] = 0.5f * v * (1.0f + erff(v * 0.70710678118654752440f));
        }
        float g[16];
        #pragma unroll
        for (int p = 0; p < 16; ++p) {
            float acc = gb2[p];
            #pragma unroll
            for (int q = 0; q < 16; ++q) acc = fmaf(h1[q], gw2[p * 16 + q], acc);
            g[p] = 1.0f / (1.0f + expf(-acc));
        }
        // fold beta*vm[t] (output) and vm[t-dly] (input mask) into taps
        const float sc = beta[0] * vm_s[gi + 15][gm];
        float eff16[16];
        #pragma unroll
        for (int dly = 0; dly < 16; ++dly) {
            float acc = 0.0f;
            #pragma unroll
            for (int p = 0; p < 16; ++p) acc = fmaf(Ks[p * 16 + 15 - dly], g[p], acc);
            eff16[dly] = acc * vm_s[gi + 15 - dly][gm] * sc;
        }
        float4* ep = (float4*)&effs[gm][gi][0];
        ep[0] = make_float4(eff16[0],  eff16[1],  eff16[2],  eff16[3]);
        ep[1] = make_float4(eff16[4],  eff16[5],  eff16[6],  eff16[7]);
        ep[2] = make_float4(eff16[8],  eff16[9],  eff16[10], eff16[11]);
        ep[3] = make_float4(eff16[12], eff16[13], eff16[14], eff16[15]);
    }
    __syncthreads();   // effs visible

    // --- phase 3: synthesis, wave w = m, 16 t x 128 d from zr + broadcast effs ---
    #pragma unroll
    for (int i = 0; i < TC; ++i) {
        const float4 e0 = *(const float4*)&effs[m][i][0];
        const float4 e1 = *(const float4*)&effs[m][i][4];
        const float4 e2 = *(const float4*)&effs[m][i][8];
        const float4 e3 = *(const float4*)&effs[m][i][12];
        float px = 0.0f, py = 0.0f;
        #define ACC(EV, DLY) { const float2 zv = zr[15 + i - (DLY)]; \
                               px = fmaf((EV), zv.x, px); py = fmaf((EV), zv.y, py); }
        ACC(e0.x, 0)  ACC(e0.y, 1)  ACC(e0.z, 2)  ACC(e0.w, 3)
        ACC(e1.x, 4)  ACC(e1.y, 5)  ACC(e1.z, 6)  ACC(e1.w, 7)
        ACC(e2.x, 8)  ACC(e2.y, 9)  ACC(e2.z, 10) ACC(e2.w, 11)
        ACC(e3.x, 12) ACC(e3.y, 13) ACC(e3.z, 14) ACC(e3.w, 15)
        #undef ACC
        const float2 zraw = zr[15 + i];
        float2 hv;
        hv.x = zraw.x + px;            // beta & masks folded into effs
        hv.y = zraw.y + py;
        const int t = t0 + i;
        *(float2*)(out + (((size_t)b * NT + t) * NM + m) * ND + lane * 2) = hv;
    }
}

extern "C" void kernel_launch(void* const* d_in, const int* in_sizes, int n_in,
                              void* d_out, int out_size, void* d_ws, size_t ws_size,
                              hipStream_t stream) {
    const float* z    = (const float*)d_in[0];
    const float* vm   = (const float*)d_in[1];
    const float* gw1  = (const float*)d_in[2];
    const float* gb1  = (const float*)d_in[3];
    const float* gw2  = (const float*)d_in[4];
    const float* gb2  = (const float*)d_in[5];
    const float* beta = (const float*)d_in[6];
    float* out = (float*)d_out;

    rama_one_k<<<NB * (NT / TC), 512, 0, stream>>>(
        z, vm, gw1, gb1, gw2, gb2, beta, out);
}